// Round 15
// baseline (45.524 us; speedup 1.0000x reference)
//
#include <hip/hip_runtime.h>
#include <hip/hip_bf16.h>
#include <math.h>

#define BB 64
#define HH 80
#define WW 3000
#define RAD 16
#define TW 48             // output columns per item
#define NLOAD 80          // loaded columns = TW + 2*16 halo
#define XSW 80            // f32 Xs words/row: NO pad (global_load_lds linear dest)
#define HXS 116           // Hxp col stride: 112 raw rows + 4 pad (116 % 32 == 20 -> b128 bank-spread)
#define NSTRIP 63         // ceil(3000/48)
#define NITEMS (BB * NSTRIP)   // 4032 work items
#define NBLK 512          // persistent blocks = exactly 2 resident per CU
#define NT 1024
#define EPSF 1e-8f

#define XSA_OFF 0
#define XSB_OFF (HH * XSW)              // 6400
#define HXP_OFF (2 * HH * XSW)          // 12800
#define ICH_OFF (HXP_OFF + TW * HXS)    // 18368 (byte 73472, 16B-aligned)
#define TOT_WORDS (ICH_OFF + HH)        // 18448 words = 73792 B -> 2 blocks/CU (32/32 wave slots)

typedef float f32x2 __attribute__((ext_vector_type(2)));
typedef float f32x4 __attribute__((ext_vector_type(4)));

__device__ __forceinline__ float bflo(uint32_t w) { return __uint_as_float(w << 16); }
__device__ __forceinline__ float bfhi(uint32_t w) { return __uint_as_float(w & 0xffff0000u); }
__device__ __forceinline__ uint32_t packbf2(float lo, float hi) {
    union { __hip_bfloat162 h2; uint32_t u; } u;
    u.h2 = __hip_bfloat162(__float2bfloat16(lo), __float2bfloat16(hi));
    return u.u;
}
__device__ __forceinline__ f32x2 uw(uint32_t w) {
    f32x2 r; r.x = bflo(w); r.y = bfhi(w); return r;
}

#if defined(__has_builtin)
#if __has_builtin(__builtin_amdgcn_global_load_lds)
#define HAVE_GLL 1
__device__ __forceinline__ void gload_lds16(const float* g, float* l) {
    __builtin_amdgcn_global_load_lds(
        (const __attribute__((address_space(1))) void*)g,
        (__attribute__((address_space(3))) void*)l, 16, 0, 0);
}
#endif
#endif

// stage one item's 80x80 f32 window into xbuf (LDS). Interior: DMA. Edge: scalar fallback.
__device__ __forceinline__ void stage_item(const float* __restrict__ in, int w, float* xbuf, int t) {
    const int b     = w / NSTRIP;
    const int strip = w - b * NSTRIP;
    const int c0    = strip * TW;
    const float* inb = in + (size_t)b * (HH * WW);
#ifdef HAVE_GLL
    if ((c0 >= 16) && (c0 - 16 + NLOAD <= WW)) {
        const float* gsrc = inb + (c0 - 16);
        {
            const int ck = t;                       // 1600 chunks of 16B
            const int row = ck / 20, m = ck - row * 20;
            gload_lds16(gsrc + (size_t)row * WW + 4 * m, xbuf + 4 * ck);
        }
        if (t < 576) {
            const int ck = t + NT;
            const int row = ck / 20, m = ck - row * 20;
            gload_lds16(gsrc + (size_t)row * WW + 4 * m, xbuf + 4 * ck);
        }
        return;
    }
#endif
    #pragma unroll
    for (int it = 0; it < 2; ++it) {
        const int id = t + it * NT;
        if (it == 0 || id < 1600) {
            const int row = id / 20, q = id - row * 20;
            const int gc  = c0 - 16 + 4 * q;
            const float* rp = inb + (size_t)row * WW;
            f32x4 v;
            if (gc >= 0 && gc + 4 <= WW) {
                v = *(const f32x4*)(rp + gc);
            } else {
                v.x = (gc     >= 0 && gc     < WW) ? rp[gc]     : 0.f;
                v.y = (gc + 1 >= 0 && gc + 1 < WW) ? rp[gc + 1] : 0.f;
                v.z = (gc + 2 >= 0 && gc + 2 < WW) ? rp[gc + 2] : 0.f;
                v.w = (gc + 3 >= 0 && gc + 3 < WW) ? rp[gc + 3] : 0.f;
            }
            *(f32x4*)(xbuf + 4 * id) = v;
        }
    }
}

// compile-time-folding element selectors (named registers only — no arrays/unions)
#define E4(V, J) ((J) == 0 ? (V).x : ((J) == 1 ? (V).y : ((J) == 2 ? (V).z : (V).w)))
#define F48(Q) E4((Q) < 4 ? G0 : (Q) < 8 ? G1 : (Q) < 12 ? G2 : (Q) < 16 ? G3 : (Q) < 20 ? G4 : \
                  (Q) < 24 ? G5 : (Q) < 28 ? G6 : (Q) < 32 ? G7 : (Q) < 36 ? G8 : \
                  (Q) < 40 ? G9 : (Q) < 44 ? G10 : G11, (Q) & 3)
#define W40(Q) E4((Q) < 4 ? v0 : (Q) < 8 ? v1 : (Q) < 12 ? v2 : (Q) < 16 ? v3 : (Q) < 20 ? v4 : \
                  (Q) < 24 ? v5 : (Q) < 28 ? v6 : (Q) < 32 ? v7 : (Q) < 36 ? v8 : v9, (Q) & 3)

__global__ __launch_bounds__(NT, 8)
void localnorm_kernel(const float* __restrict__ in, float* __restrict__ out) {
    extern __shared__ uint32_t smem[];
    float*    smemf = (float*)smem;
    uint32_t* Hxp   = smem + HXP_OFF;        // Hxp[col][raw_r] at col*HXS + raw_r; raw_r = logical+16
    float*   inv_ch = (float*)(smem + ICH_OFF);
    float*   XsA    = smemf + XSA_OFF;
    float*   XsB    = smemf + XSB_OFF;

    const int t   = threadIdx.x;
    const int bid = blockIdx.x;

    // phase 0 (once): per-row reciprocals + zero Hxp pad rows (raw 0..15 and 96..111), 48 cols
    if (t < HH) {
        int lo = max(t - RAD, 0), hi = min(t + RAD, HH - 1);
        inv_ch[t] = 1.0f / (float)(hi - lo + 1);
    }
    if (t < 384) {
        const int col = t >> 3;
        const int c8  = t & 7;
        const int off = col * HXS + ((c8 < 4) ? (c8 * 4) : (96 + (c8 - 4) * 4));
        *(uint4*)(Hxp + off) = make_uint4(0u, 0u, 0u, 0u);
    }

    // prologue: stage first item
    stage_item(in, bid, XsA, t);
    __syncthreads();

    int cur = 0;
    #pragma unroll 1
    for (int w = bid; w < NITEMS; w += NBLK) {
        float* Xs = cur ? XsB : XsA;
        float* Xn = cur ? XsA : XsB;
        // issue next item's DMA (zero registers held; flies under P2/P3)
        if (w + NBLK < NITEMS) stage_item(in, w + NBLK, Xn, t);

        const int b     = w / NSTRIP;
        const int strip = w - b * NSTRIP;
        const int c0    = strip * TW;

        // P2: fused horizontal 33-tap sums of x AND x^2 from f32 Xs, 16 cols/thread.
        // 80 rows x 3 segs = 240 threads; 12 f32x4 LDS reads each.
        {
            const int row = t % HH;
            const int seg = t / HH;       // 0..2 active
            if (seg < 3) {
                const float* xr = Xs + row * XSW + seg * 16;
                f32x4 G0  = *(const f32x4*)(xr);
                f32x4 G1  = *(const f32x4*)(xr + 4);
                f32x4 G2  = *(const f32x4*)(xr + 8);
                f32x4 G3  = *(const f32x4*)(xr + 12);
                f32x4 G4  = *(const f32x4*)(xr + 16);
                f32x4 G5  = *(const f32x4*)(xr + 20);
                f32x4 G6  = *(const f32x4*)(xr + 24);
                f32x4 G7  = *(const f32x4*)(xr + 28);
                f32x4 G8  = *(const f32x4*)(xr + 32);
                f32x4 G9  = *(const f32x4*)(xr + 36);
                f32x4 G10 = *(const f32x4*)(xr + 40);
                f32x4 G11 = *(const f32x4*)(xr + 44);
                float e32 = F48(32);
                float axA = e32, axB = 0.f;
                float qxA = e32 * e32, qxB = 0.f;
                #pragma unroll
                for (int q = 0; q < 32; q += 2) {
                    float fa = F48(q), fb = F48(q + 1);
                    axA += fa;                 axB += fb;
                    qxA = fmaf(fa, fa, qxA);   qxB = fmaf(fb, fb, qxB);
                }
                float ax = axA + axB, axx = qxA + qxB;
                uint32_t* hw = Hxp + (seg * 16) * HXS + row + 16;
                #pragma unroll
                for (int k = 0; k < 8; ++k) {
                    float fs = F48(2 * k), fe = F48(2 * k + 33);
                    float a1x  = ax - fs + fe;
                    float a1xx = fmaf(fe, fe, fmaf(-fs, fs, axx));
                    hw[(2 * k) * HXS]     = packbf2(ax, axx);
                    hw[(2 * k + 1) * HXS] = packbf2(a1x, a1xx);
                    if (k != 7) {
                        float fs2 = F48(2 * k + 1), fe2 = F48(2 * k + 34);
                        ax  = a1x - fs2 + fe2;
                        axx = fmaf(fe2, fe2, fmaf(-fs2, fs2, a1xx));
                    }
                }
            }
        }
        __syncthreads();

        // P3: vertical 33-tap sums of (Sx,Sxx) via pk_add, bands of 8 rows.
        // 48 cols x 10 bands = 480 threads; 10 contiguous b128 reads.
        {
            const int c    = t % TW;
            const int band = t / TW;
            const int gc   = c0 + c;
            if (band < 10 && gc < WW) {
                const int r0 = band * 8;
                const uint32_t* hp = Hxp + c * HXS + r0;   // raw rows r0 .. r0+39
                uint4 v0 = *(const uint4*)(hp);
                uint4 v1 = *(const uint4*)(hp + 4);
                uint4 v2 = *(const uint4*)(hp + 8);
                uint4 v3 = *(const uint4*)(hp + 12);
                uint4 v4 = *(const uint4*)(hp + 16);
                uint4 v5 = *(const uint4*)(hp + 20);
                uint4 v6 = *(const uint4*)(hp + 24);
                uint4 v7 = *(const uint4*)(hp + 28);
                uint4 v8 = *(const uint4*)(hp + 32);
                uint4 v9 = *(const uint4*)(hp + 36);
                f32x2 aA = uw(W40(32));
                f32x2 aB; aB.x = 0.f; aB.y = 0.f;
                #pragma unroll
                for (int q = 0; q < 32; q += 2) {
                    aA += uw(W40(q));
                    aB += uw(W40(q + 1));
                }
                f32x2 acc = aA + aB;                       // {Sx_v, Sxx_v}
                const float icw = 1.0f / (float)(min(gc + RAD, WW - 1) - max(gc - RAD, 0) + 1);
                f32x4 f4a = *(const f32x4*)(inv_ch + r0);
                f32x4 f4b = *(const f32x4*)(inv_ch + r0 + 4);
                float* outb = out + (size_t)b * (HH * WW);
                #pragma unroll
                for (int k = 0; k < 8; ++k) {
                    const int r = r0 + k;
                    const float ninv = E4(k < 4 ? f4a : f4b, k & 3) * icw;
                    f32x2 me = acc * ninv;                 // {mean, E[x^2]} via v_pk_mul
                    float var = fmaxf(me.y - me.x * me.x, 1e-24f);
#if defined(__has_builtin) && __has_builtin(__builtin_amdgcn_rsqf)
                    float isd = __builtin_amdgcn_rsqf(var);
#else
                    float isd = __builtin_amdgcn_rcpf(__builtin_amdgcn_sqrtf(var) + EPSF);
#endif
                    float xv = Xs[r * XSW + c + 16];       // f32 x, no unpack
                    outb[(size_t)r * WW + gc] = (xv - me.x) * isd;
                    if (k != 7) {
                        acc += uw(W40(k + 33)) - uw(W40(k));   // 2x v_pk_add_f32
                    }
                }
            }
        }
        __syncthreads();   // drains next-item DMA (vmcnt) + protects Xs/Hxp reuse
        cur ^= 1;
    }
}

extern "C" void kernel_launch(void* const* d_in, const int* in_sizes, int n_in,
                              void* d_out, int out_size, void* d_ws, size_t ws_size,
                              hipStream_t stream) {
    const float* in = (const float*)d_in[0];
    float* out = (float*)d_out;

    const size_t lds_bytes = (size_t)TOT_WORDS * sizeof(uint32_t);  // 73792
    static bool attr_set = false;
    if (!attr_set) {
        (void)hipFuncSetAttribute((const void*)localnorm_kernel,
                                  hipFuncAttributeMaxDynamicSharedMemorySize,
                                  (int)lds_bytes);
        attr_set = true;
    }

    dim3 grid(NBLK);   // 512 persistent blocks = exactly 2 resident per CU
    dim3 block(NT);
    localnorm_kernel<<<grid, block, lds_bytes, stream>>>(in, out);
}

// Round 16
// 37.699 us; speedup vs baseline: 1.2075x; 1.2075x over previous
//
#include <hip/hip_runtime.h>
#include <hip/hip_bf16.h>
#include <math.h>

#define BB 64
#define HH 80
#define WW 3000
#define RAD 16
#define TW 80             // output columns per strip
#define NLOAD 112         // loaded columns = TW + 2*16 halo
#define XSW 112           // f32 Xs words/row: NO pad (global_load_lds needs linear dest)
#define HXS 116           // Hxp col stride: 112 raw rows + 4 pad (116 % 32 == 20 -> b128 bank-spread)
#define NSTRIP 38         // ceil(3000/80)
#define NT 1024
#define EPSF 1e-8f

#define XS_WORDS (HH * XSW)             // 8960
#define HXP_OFF  XS_WORDS
#define HXP_WORDS (TW * HXS)            // 9280
#define ICH_OFF  (XS_WORDS + HXP_WORDS) // 18240 (byte 72960, 16B-aligned)
#define TOT_WORDS (ICH_OFF + HH)        // 18320 words = 73280 B -> 2 blocks/CU (32/32 wave slots)

typedef float f32x2 __attribute__((ext_vector_type(2)));
typedef float f32x4 __attribute__((ext_vector_type(4)));

__device__ __forceinline__ float bflo(uint32_t w) { return __uint_as_float(w << 16); }
__device__ __forceinline__ float bfhi(uint32_t w) { return __uint_as_float(w & 0xffff0000u); }
__device__ __forceinline__ uint32_t packbf2(float lo, float hi) {
    union { __hip_bfloat162 h2; uint32_t u; } u;
    u.h2 = __hip_bfloat162(__float2bfloat16(lo), __float2bfloat16(hi));
    return u.u;
}
__device__ __forceinline__ f32x2 uw(uint32_t w) {
    f32x2 r; r.x = bflo(w); r.y = bfhi(w); return r;
}

#if defined(__has_builtin)
#if __has_builtin(__builtin_amdgcn_global_load_lds)
#define HAVE_GLL 1
__device__ __forceinline__ void gload_lds16(const float* g, float* l) {
    __builtin_amdgcn_global_load_lds(
        (const __attribute__((address_space(1))) void*)g,
        (__attribute__((address_space(3))) void*)l, 16, 0, 0);
}
#endif
#endif

// stage one 40-row half (1120 16B chunks) via DMA; base = starting chunk (0 or 1120)
#ifdef HAVE_GLL
__device__ __forceinline__ void dma_half(const float* __restrict__ gsrc, float* __restrict__ lds,
                                         int t, int base) {
    {
        const int ck  = base + t;
        const int row = ck / 28, m = ck - row * 28;
        gload_lds16(gsrc + (size_t)row * WW + 4 * m, lds + 4 * ck);
    }
    if (t < 96) {
        const int ck  = base + 1024 + t;
        const int row = ck / 28, m = ck - row * 28;
        gload_lds16(gsrc + (size_t)row * WW + 4 * m, lds + 4 * ck);
    }
}
#endif

// bounds-checked fallback half (edge strips)
__device__ __forceinline__ void fb_half(const float* __restrict__ inb, int c0,
                                        float* __restrict__ lds, int t, int base) {
    #pragma unroll
    for (int it = 0; it < 2; ++it) {
        if (it == 0 || t < 96) {
            const int id  = base + t + it * NT;
            const int row = id / 28, q = id - row * 28;
            const int gc  = c0 - 16 + 4 * q;
            const float* rp = inb + (size_t)row * WW;
            f32x4 v;
            if (gc >= 0 && gc + 4 <= WW) {
                v = *(const f32x4*)(rp + gc);
            } else {
                v.x = (gc     >= 0 && gc     < WW) ? rp[gc]     : 0.f;
                v.y = (gc + 1 >= 0 && gc + 1 < WW) ? rp[gc + 1] : 0.f;
                v.z = (gc + 2 >= 0 && gc + 2 < WW) ? rp[gc + 2] : 0.f;
                v.w = (gc + 3 >= 0 && gc + 3 < WW) ? rp[gc + 3] : 0.f;
            }
            *(f32x4*)(lds + 4 * id) = v;
        }
    }
}

// compile-time-folding element selectors (named registers only — no arrays/unions)
#define E4(V, J) ((J) == 0 ? (V).x : ((J) == 1 ? (V).y : ((J) == 2 ? (V).z : (V).w)))
#define F48(Q) E4((Q) < 4 ? G0 : (Q) < 8 ? G1 : (Q) < 12 ? G2 : (Q) < 16 ? G3 : (Q) < 20 ? G4 : \
                  (Q) < 24 ? G5 : (Q) < 28 ? G6 : (Q) < 32 ? G7 : (Q) < 36 ? G8 : \
                  (Q) < 40 ? G9 : (Q) < 44 ? G10 : G11, (Q) & 3)
#define W48(Q) E4((Q) < 4 ? R0 : (Q) < 8 ? R1 : (Q) < 12 ? R2 : (Q) < 16 ? R3 : (Q) < 20 ? R4 : \
                  (Q) < 24 ? R5 : (Q) < 28 ? R6 : (Q) < 32 ? R7 : (Q) < 36 ? R8 : \
                  (Q) < 40 ? R9 : (Q) < 44 ? R10 : R11, (Q) & 3)
#define F16(K) E4((K) < 4 ? f0 : (K) < 8 ? f1 : (K) < 12 ? f2 : f3, (K) & 3)

// P2 body: horizontal 33-tap (Sx,Sxx) for one (row, seg-of-16-cols)
__device__ __forceinline__ void p2_body(const float* __restrict__ smemf,
                                        uint32_t* __restrict__ Hxp, int row, int seg) {
    const float* xr = smemf + row * XSW + seg * 16;
    f32x4 G0  = *(const f32x4*)(xr);
    f32x4 G1  = *(const f32x4*)(xr + 4);
    f32x4 G2  = *(const f32x4*)(xr + 8);
    f32x4 G3  = *(const f32x4*)(xr + 12);
    f32x4 G4  = *(const f32x4*)(xr + 16);
    f32x4 G5  = *(const f32x4*)(xr + 20);
    f32x4 G6  = *(const f32x4*)(xr + 24);
    f32x4 G7  = *(const f32x4*)(xr + 28);
    f32x4 G8  = *(const f32x4*)(xr + 32);
    f32x4 G9  = *(const f32x4*)(xr + 36);
    f32x4 G10 = *(const f32x4*)(xr + 40);
    f32x4 G11 = *(const f32x4*)(xr + 44);
    float e32 = F48(32);
    float axA = e32, axB = 0.f;
    float qxA = e32 * e32, qxB = 0.f;
    #pragma unroll
    for (int q = 0; q < 32; q += 2) {
        float fa = F48(q), fb = F48(q + 1);
        axA += fa;                 axB += fb;
        qxA = fmaf(fa, fa, qxA);   qxB = fmaf(fb, fb, qxB);
    }
    float ax = axA + axB, axx = qxA + qxB;
    uint32_t* hw = Hxp + (seg * 16) * HXS + row + 16;
    #pragma unroll
    for (int k = 0; k < 8; ++k) {
        float fs = F48(2 * k), fe = F48(2 * k + 33);
        float a1x  = ax - fs + fe;
        float a1xx = fmaf(fe, fe, fmaf(-fs, fs, axx));
        hw[(2 * k) * HXS]     = packbf2(ax, axx);
        hw[(2 * k + 1) * HXS] = packbf2(a1x, a1xx);
        if (k != 7) {
            float fs2 = F48(2 * k + 1), fe2 = F48(2 * k + 34);
            ax  = a1x - fs2 + fe2;
            axx = fmaf(fe2, fe2, fmaf(-fs2, fs2, a1xx));
        }
    }
}

__global__ __launch_bounds__(NT, 8)
void localnorm_kernel(const float* __restrict__ in, float* __restrict__ out) {
    extern __shared__ uint32_t smem[];
    float*    smemf = (float*)smem;
    uint32_t* Hxp   = smem + HXP_OFF;        // Hxp[col][raw_r] at col*HXS + raw_r; raw_r = logical+16
    float*   inv_ch = (float*)(smem + ICH_OFF);

    const int t     = threadIdx.x;
    const int strip = blockIdx.x % NSTRIP;
    const int b     = blockIdx.x / NSTRIP;
    const int c0    = strip * TW;
    const float* inb = in + (size_t)b * (HH * WW);

    // phase 0: per-row reciprocals + zero Hxp pad rows (raw 0..15 and 96..111) for 80 cols
    if (t < HH) {
        int lo = max(t - RAD, 0), hi = min(t + RAD, HH - 1);
        inv_ch[t] = 1.0f / (float)(hi - lo + 1);
    }
    if (t < 640) {
        const int col = t >> 3;
        const int c8  = t & 7;
        const int off = col * HXS + ((c8 < 4) ? (c8 * 4) : (96 + (c8 - 4) * 4));
        *(uint4*)(Hxp + off) = make_uint4(0u, 0u, 0u, 0u);
    }

    bool dma = false;
#ifdef HAVE_GLL
    dma = (c0 >= 16) && (c0 - 16 + NLOAD <= WW);
#endif

    // ---- stage half A (rows 0..39) ----
    if (dma) {
#ifdef HAVE_GLL
        dma_half(inb + (c0 - 16), smemf, t, 0);
#endif
    } else {
        fb_half(inb, c0, smemf, t, 0);
    }
    __syncthreads();   // drains half-A DMA

    // ---- issue half B (rows 40..79); then P2 on rows 0..39 (hides B's HBM time) ----
    if (dma) {
#ifdef HAVE_GLL
        dma_half(inb + (c0 - 16), smemf, t, 1120);
#endif
    } else {
        fb_half(inb, c0, smemf, t, 1120);
    }
    {   // P2-A: seg = t%5, row = t/5; rows 0..39 <=> t < 200
        if (t < 200) p2_body(smemf, Hxp, t / 5, t % 5);
    }
    __syncthreads();   // drains half-B DMA (mostly complete under P2-A)

    // ---- P2-B: rows 40..79 <=> 200 <= t < 400 ----
    if (t >= 200 && t < 400) p2_body(smemf, Hxp, t / 5, t % 5);
    __syncthreads();

    // ---- P3: vertical 33-tap sums of (Sx,Sxx) via pk_add, bands of 16 rows. ----
    // 80 cols x 5 bands = 400 threads; 12 contiguous b128 reads (words r0..r0+47).
    {
        const int c    = t % TW;
        const int band = t / TW;
        const int gc   = c0 + c;
        if (band < 5 && gc < WW) {
            const int r0 = band * 16;
            const uint32_t* hp = Hxp + c * HXS + r0;   // raw rows r0 .. r0+47
            uint4 R0  = *(const uint4*)(hp);
            uint4 R1  = *(const uint4*)(hp + 4);
            uint4 R2  = *(const uint4*)(hp + 8);
            uint4 R3  = *(const uint4*)(hp + 12);
            uint4 R4  = *(const uint4*)(hp + 16);
            uint4 R5  = *(const uint4*)(hp + 20);
            uint4 R6  = *(const uint4*)(hp + 24);
            uint4 R7  = *(const uint4*)(hp + 28);
            uint4 R8  = *(const uint4*)(hp + 32);
            uint4 R9  = *(const uint4*)(hp + 36);
            uint4 R10 = *(const uint4*)(hp + 40);
            uint4 R11 = *(const uint4*)(hp + 44);
            f32x2 aA = uw(W48(32));
            f32x2 aB; aB.x = 0.f; aB.y = 0.f;
            #pragma unroll
            for (int q = 0; q < 32; q += 2) {
                aA += uw(W48(q));
                aB += uw(W48(q + 1));
            }
            f32x2 acc = aA + aB;                       // {Sx_v, Sxx_v}
            const float icw = 1.0f / (float)(min(gc + RAD, WW - 1) - max(gc - RAD, 0) + 1);
            f32x4 f0 = *(const f32x4*)(inv_ch + r0);
            f32x4 f1 = *(const f32x4*)(inv_ch + r0 + 4);
            f32x4 f2 = *(const f32x4*)(inv_ch + r0 + 8);
            f32x4 f3 = *(const f32x4*)(inv_ch + r0 + 12);
            float* outb = out + (size_t)b * (HH * WW);
            #pragma unroll
            for (int k = 0; k < 16; ++k) {
                const int r = r0 + k;
                const float ninv = F16(k) * icw;
                f32x2 me = acc * ninv;                 // {mean, E[x^2]} via v_pk_mul
                float var = fmaxf(me.y - me.x * me.x, 1e-24f);
#if defined(__has_builtin) && __has_builtin(__builtin_amdgcn_rsqf)
                float isd = __builtin_amdgcn_rsqf(var);
#else
                float isd = __builtin_amdgcn_rcpf(__builtin_amdgcn_sqrtf(var) + EPSF);
#endif
                float xv = smemf[r * XSW + c + 16];    // f32 x, no unpack
                outb[(size_t)r * WW + gc] = (xv - me.x) * isd;
                if (k != 15) {
                    acc += uw(W48(k + 33)) - uw(W48(k));   // 2x v_pk_add_f32
                }
            }
        }
    }
}

extern "C" void kernel_launch(void* const* d_in, const int* in_sizes, int n_in,
                              void* d_out, int out_size, void* d_ws, size_t ws_size,
                              hipStream_t stream) {
    const float* in = (const float*)d_in[0];
    float* out = (float*)d_out;

    const size_t lds_bytes = (size_t)TOT_WORDS * sizeof(uint32_t);  // 73280
    static bool attr_set = false;
    if (!attr_set) {
        (void)hipFuncSetAttribute((const void*)localnorm_kernel,
                                  hipFuncAttributeMaxDynamicSharedMemorySize,
                                  (int)lds_bytes);
        attr_set = true;
    }

    dim3 grid(BB * NSTRIP);
    dim3 block(NT);
    localnorm_kernel<<<grid, block, lds_bytes, stream>>>(in, out);
}

// Round 17
// 35.585 us; speedup vs baseline: 1.2793x; 1.0594x over previous
//
#include <hip/hip_runtime.h>
#include <hip/hip_bf16.h>
#include <math.h>

#define BB 64
#define HH 80
#define WW 3000
#define RAD 16
#define TW 80             // output columns per strip
#define NLOAD 112         // loaded columns = TW + 2*16 halo
#define XSW 112           // f32 Xs words/row: NO pad (global_load_lds needs linear dest)
#define HXS 116           // Hxp col stride: 112 raw rows + 4 pad (116 % 32 == 20 -> b128 bank-spread)
#define NSTRIP 38         // ceil(3000/80)
#define NT 1024
#define EPSF 1e-8f

#define XS_WORDS (HH * XSW)             // 8960
#define HXP_OFF  XS_WORDS
#define HXP_WORDS (TW * HXS)            // 9280
#define ICH_OFF  (XS_WORDS + HXP_WORDS) // 18240 (byte 72960, 16B-aligned)
#define TOT_WORDS (ICH_OFF + HH)        // 18320 words = 73280 B -> 2 blocks/CU (32/32 wave slots)

typedef float f32x2 __attribute__((ext_vector_type(2)));
typedef float f32x4 __attribute__((ext_vector_type(4)));

__device__ __forceinline__ float bflo(uint32_t w) { return __uint_as_float(w << 16); }
__device__ __forceinline__ float bfhi(uint32_t w) { return __uint_as_float(w & 0xffff0000u); }
__device__ __forceinline__ uint32_t packbf2(float lo, float hi) {
    union { __hip_bfloat162 h2; uint32_t u; } u;
    u.h2 = __hip_bfloat162(__float2bfloat16(lo), __float2bfloat16(hi));
    return u.u;
}
// unpack a bf16-packed word into f32x2 {lo, hi}; pk_add accumulates both halves
__device__ __forceinline__ f32x2 uw(uint32_t w) {
    f32x2 r; r.x = bflo(w); r.y = bfhi(w); return r;
}

#if defined(__has_builtin)
#if __has_builtin(__builtin_amdgcn_global_load_lds)
#define HAVE_GLL 1
__device__ __forceinline__ void gload_lds16(const float* g, float* l) {
    __builtin_amdgcn_global_load_lds(
        (const __attribute__((address_space(1))) void*)g,
        (__attribute__((address_space(3))) void*)l, 16, 0, 0);
}
#endif
#endif

// compile-time-folding element selectors (named registers only — no arrays/unions)
#define E4(V, J) ((J) == 0 ? (V).x : ((J) == 1 ? (V).y : ((J) == 2 ? (V).z : (V).w)))
#define F48(Q) E4((Q) < 4 ? G0 : (Q) < 8 ? G1 : (Q) < 12 ? G2 : (Q) < 16 ? G3 : (Q) < 20 ? G4 : \
                  (Q) < 24 ? G5 : (Q) < 28 ? G6 : (Q) < 32 ? G7 : (Q) < 36 ? G8 : \
                  (Q) < 40 ? G9 : (Q) < 44 ? G10 : G11, (Q) & 3)
#define W48(Q) E4((Q) < 4 ? R0 : (Q) < 8 ? R1 : (Q) < 12 ? R2 : (Q) < 16 ? R3 : (Q) < 20 ? R4 : \
                  (Q) < 24 ? R5 : (Q) < 28 ? R6 : (Q) < 32 ? R7 : (Q) < 36 ? R8 : \
                  (Q) < 40 ? R9 : (Q) < 44 ? R10 : R11, (Q) & 3)
#define F16(K) E4((K) < 4 ? f0 : (K) < 8 ? f1 : (K) < 12 ? f2 : f3, (K) & 3)

__global__ __launch_bounds__(NT, 8)
void localnorm_kernel(const float* __restrict__ in, float* __restrict__ out) {
    extern __shared__ uint32_t smem[];
    float*    smemf = (float*)smem;
    uint32_t* Hxp   = smem + HXP_OFF;        // Hxp[col][raw_r] at col*HXS + raw_r; raw_r = logical+16
    float*   inv_ch = (float*)(smem + ICH_OFF);

    const int t     = threadIdx.x;
    const int strip = blockIdx.x % NSTRIP;
    const int b     = blockIdx.x / NSTRIP;
    const int c0    = strip * TW;
    const float* inb = in + (size_t)b * (HH * WW);

    // phase 0: per-row reciprocals + zero Hxp pad rows (raw 0..15 and 96..111) for 80 cols
    if (t < HH) {
        int lo = max(t - RAD, 0), hi = min(t + RAD, HH - 1);
        inv_ch[t] = 1.0f / (float)(hi - lo + 1);
    }
    if (t < 640) {
        const int col = t >> 3;
        const int c8  = t & 7;
        const int off = col * HXS + ((c8 < 4) ? (c8 * 4) : (96 + (c8 - 4) * 4));
        *(uint4*)(Hxp + off) = make_uint4(0u, 0u, 0u, 0u);
    }

    // phase 1: stage 112 cols x 80 rows of f32 into Xs.
    // Interior strips: pure DMA via global_load_lds (2240 16B chunks, linear LDS dest).
    // Edge strips (0, 37): scalar bounds-checked fallback.
    bool dma = false;
#ifdef HAVE_GLL
    dma = (c0 >= 16) && (c0 + NLOAD - 16 <= WW);
#endif
    if (dma) {
#ifdef HAVE_GLL
        const float* gsrc = inb + (c0 - 16);
        #pragma unroll
        for (int i = 0; i < 3; ++i) {
            const int ck = t + i * NT;                 // chunk id: 4 words at Xs word 4*ck
            if (i < 2 || ck < 2240) {
                const int row = ck / 28;               // 28 chunks per 112-word row
                const int m   = ck - row * 28;
                gload_lds16(gsrc + (size_t)row * WW + 4 * m, smemf + 4 * ck);
            }
        }
#endif
    } else {
        #pragma unroll
        for (int it = 0; it < 3; ++it) {
            const int id = t + it * NT;
            if (it < 2 || id < 2240) {
                const int row = id / 28;
                const int q   = id - row * 28;
                const int gc  = c0 - 16 + 4 * q;
                const float* rp = inb + (size_t)row * WW;
                f32x4 v;
                if (gc >= 0 && gc + 4 <= WW) {
                    v = *(const f32x4*)(rp + gc);
                } else {
                    v.x = (gc     >= 0 && gc     < WW) ? rp[gc]     : 0.f;
                    v.y = (gc + 1 >= 0 && gc + 1 < WW) ? rp[gc + 1] : 0.f;
                    v.z = (gc + 2 >= 0 && gc + 2 < WW) ? rp[gc + 2] : 0.f;
                    v.w = (gc + 3 >= 0 && gc + 3 < WW) ? rp[gc + 3] : 0.f;
                }
                *(f32x4*)(smemf + row * XSW + 4 * q) = v;
            }
        }
    }
    __syncthreads();   // drains vmcnt -> DMA'd Xs visible

    // phase 2: fused horizontal 33-tap sums of x AND x^2 from f32 Xs (no unpack);
    // bf16-packed (Sx,Sxx) word per col into Hxp. 80 rows x 5 segs of 16 cols = 400 threads.
    {
        const int row = t % HH;
        const int seg = t / HH;       // 0..4 active
        if (seg < 5) {
            const float* xr = smemf + row * XSW + seg * 16;
            f32x4 G0  = *(const f32x4*)(xr);
            f32x4 G1  = *(const f32x4*)(xr + 4);
            f32x4 G2  = *(const f32x4*)(xr + 8);
            f32x4 G3  = *(const f32x4*)(xr + 12);
            f32x4 G4  = *(const f32x4*)(xr + 16);
            f32x4 G5  = *(const f32x4*)(xr + 20);
            f32x4 G6  = *(const f32x4*)(xr + 24);
            f32x4 G7  = *(const f32x4*)(xr + 28);
            f32x4 G8  = *(const f32x4*)(xr + 32);
            f32x4 G9  = *(const f32x4*)(xr + 36);
            f32x4 G10 = *(const f32x4*)(xr + 40);
            f32x4 G11 = *(const f32x4*)(xr + 44);
            // initial window F(0..32), 2-way ILP split
            float e32 = F48(32);
            float axA = e32, axB = 0.f;
            float qxA = e32 * e32, qxB = 0.f;
            #pragma unroll
            for (int q = 0; q < 32; q += 2) {
                float fa = F48(q), fb = F48(q + 1);
                axA += fa;                 axB += fb;
                qxA = fmaf(fa, fa, qxA);   qxB = fmaf(fb, fb, qxB);
            }
            float ax = axA + axB, axx = qxA + qxB;
            uint32_t* hw = Hxp + (seg * 16) * HXS + row + 16;
            #pragma unroll
            for (int k = 0; k < 8; ++k) {
                float fs = F48(2 * k), fe = F48(2 * k + 33);
                float a1x  = ax - fs + fe;
                float a1xx = fmaf(fe, fe, fmaf(-fs, fs, axx));
                hw[(2 * k) * HXS]     = packbf2(ax, axx);
                hw[(2 * k + 1) * HXS] = packbf2(a1x, a1xx);
                if (k != 7) {
                    float fs2 = F48(2 * k + 1), fe2 = F48(2 * k + 34);
                    ax  = a1x - fs2 + fe2;
                    axx = fmaf(fe2, fe2, fmaf(-fs2, fs2, a1xx));
                }
            }
        }
    }
    __syncthreads();

    // phase 3: vertical 33-tap sums of (Sx,Sxx) via pk_add, bands of 16 rows.
    // 80 cols x 5 bands = 400 threads; 12 contiguous b128 reads (words r0..r0+47).
    {
        const int c    = t % TW;
        const int band = t / TW;
        const int gc   = c0 + c;
        if (band < 5 && gc < WW) {
            const int r0 = band * 16;
            const uint32_t* hp = Hxp + c * HXS + r0;   // raw rows r0 .. r0+47
            uint4 R0  = *(const uint4*)(hp);
            uint4 R1  = *(const uint4*)(hp + 4);
            uint4 R2  = *(const uint4*)(hp + 8);
            uint4 R3  = *(const uint4*)(hp + 12);
            uint4 R4  = *(const uint4*)(hp + 16);
            uint4 R5  = *(const uint4*)(hp + 20);
            uint4 R6  = *(const uint4*)(hp + 24);
            uint4 R7  = *(const uint4*)(hp + 28);
            uint4 R8  = *(const uint4*)(hp + 32);
            uint4 R9  = *(const uint4*)(hp + 36);
            uint4 R10 = *(const uint4*)(hp + 40);
            uint4 R11 = *(const uint4*)(hp + 44);
            // init acc = sum of words 0..32 (3 ops/word via pk_add), 2-way split
            f32x2 aA = uw(W48(32));
            f32x2 aB; aB.x = 0.f; aB.y = 0.f;
            #pragma unroll
            for (int q = 0; q < 32; q += 2) {
                aA += uw(W48(q));
                aB += uw(W48(q + 1));
            }
            f32x2 acc = aA + aB;                       // {Sx_v, Sxx_v}
            const float icw = 1.0f / (float)(min(gc + RAD, WW - 1) - max(gc - RAD, 0) + 1);
            f32x4 f0 = *(const f32x4*)(inv_ch + r0);
            f32x4 f1 = *(const f32x4*)(inv_ch + r0 + 4);
            f32x4 f2 = *(const f32x4*)(inv_ch + r0 + 8);
            f32x4 f3 = *(const f32x4*)(inv_ch + r0 + 12);
            float* outb = out + (size_t)b * (HH * WW);
            #pragma unroll
            for (int k = 0; k < 16; ++k) {
                const int r = r0 + k;
                const float ninv = F16(k) * icw;
                f32x2 me = acc * ninv;                 // {mean, E[x^2]} via v_pk_mul
                float var = fmaxf(me.y - me.x * me.x, 1e-24f);
#if defined(__has_builtin) && __has_builtin(__builtin_amdgcn_rsqf)
                float isd = __builtin_amdgcn_rsqf(var);
#else
                float isd = __builtin_amdgcn_rcpf(__builtin_amdgcn_sqrtf(var) + EPSF);
#endif
                float xv = smemf[r * XSW + c + 16];    // f32 x, no unpack
                outb[(size_t)r * WW + gc] = (xv - me.x) * isd;
                if (k != 15) {
                    acc += uw(W48(k + 33)) - uw(W48(k));   // 2x v_pk_add_f32
                }
            }
        }
    }
}

extern "C" void kernel_launch(void* const* d_in, const int* in_sizes, int n_in,
                              void* d_out, int out_size, void* d_ws, size_t ws_size,
                              hipStream_t stream) {
    const float* in = (const float*)d_in[0];
    float* out = (float*)d_out;

    const size_t lds_bytes = (size_t)TOT_WORDS * sizeof(uint32_t);  // 73280
    static bool attr_set = false;
    if (!attr_set) {
        (void)hipFuncSetAttribute((const void*)localnorm_kernel,
                                  hipFuncAttributeMaxDynamicSharedMemorySize,
                                  (int)lds_bytes);
        attr_set = true;
    }

    dim3 grid(BB * NSTRIP);
    dim3 block(NT);
    localnorm_kernel<<<grid, block, lds_bytes, stream>>>(in, out);
}

// Round 18
// 35.345 us; speedup vs baseline: 1.2880x; 1.0068x over previous
//
#include <hip/hip_runtime.h>
#include <hip/hip_bf16.h>
#include <math.h>

#define BB 64
#define HH 80
#define WW 3000
#define RAD 16
#define TW 80             // output columns per strip
#define NLOAD 112         // loaded columns = TW + 2*16 halo
#define XSW 112           // f32 Xs words/row: NO pad (global_load_lds needs linear dest)
#define HXS 116           // Hxp col stride: 112 raw rows + 4 pad (116 % 32 == 20 -> b128 bank-spread)
#define NSTRIP 38         // ceil(3000/80)
#define NT 1024
#define EPSF 1e-8f

#define XS_WORDS (HH * XSW)             // 8960
#define HXP_OFF  XS_WORDS
#define HXP_WORDS (TW * HXS)            // 9280
#define ICH_OFF  (XS_WORDS + HXP_WORDS) // 18240 (byte 72960, 16B-aligned)
#define TOT_WORDS (ICH_OFF + HH)        // 18320 words = 73280 B -> 2 blocks/CU (32/32 wave slots)

typedef float f32x2 __attribute__((ext_vector_type(2)));
typedef float f32x4 __attribute__((ext_vector_type(4)));

__device__ __forceinline__ float bflo(uint32_t w) { return __uint_as_float(w << 16); }
__device__ __forceinline__ float bfhi(uint32_t w) { return __uint_as_float(w & 0xffff0000u); }
__device__ __forceinline__ uint32_t packbf2(float lo, float hi) {
    union { __hip_bfloat162 h2; uint32_t u; } u;
    u.h2 = __hip_bfloat162(__float2bfloat16(lo), __float2bfloat16(hi));
    return u.u;
}
// unpack a bf16-packed word into f32x2 {lo, hi}; pk_add accumulates both halves
__device__ __forceinline__ f32x2 uw(uint32_t w) {
    f32x2 r; r.x = bflo(w); r.y = bfhi(w); return r;
}

#if defined(__has_builtin)
#if __has_builtin(__builtin_amdgcn_global_load_lds)
#define HAVE_GLL 1
__device__ __forceinline__ void gload_lds16(const float* g, float* l) {
    __builtin_amdgcn_global_load_lds(
        (const __attribute__((address_space(1))) void*)g,
        (__attribute__((address_space(3))) void*)l, 16, 0, 0);
}
#endif
#endif

// compile-time-folding element selectors (named registers only — no arrays/unions)
#define E4(V, J) ((J) == 0 ? (V).x : ((J) == 1 ? (V).y : ((J) == 2 ? (V).z : (V).w)))
#define F48(Q) E4((Q) < 4 ? G0 : (Q) < 8 ? G1 : (Q) < 12 ? G2 : (Q) < 16 ? G3 : (Q) < 20 ? G4 : \
                  (Q) < 24 ? G5 : (Q) < 28 ? G6 : (Q) < 32 ? G7 : (Q) < 36 ? G8 : \
                  (Q) < 40 ? G9 : (Q) < 44 ? G10 : G11, (Q) & 3)
#define W48(Q) E4((Q) < 4 ? R0 : (Q) < 8 ? R1 : (Q) < 12 ? R2 : (Q) < 16 ? R3 : (Q) < 20 ? R4 : \
                  (Q) < 24 ? R5 : (Q) < 28 ? R6 : (Q) < 32 ? R7 : (Q) < 36 ? R8 : \
                  (Q) < 40 ? R9 : (Q) < 44 ? R10 : R11, (Q) & 3)
#define F16(K) E4((K) < 4 ? f0 : (K) < 8 ? f1 : (K) < 12 ? f2 : f3, (K) & 3)

__global__ __launch_bounds__(NT, 8)
void localnorm_kernel(const float* __restrict__ in, float* __restrict__ out) {
    extern __shared__ uint32_t smem[];
    float*    smemf = (float*)smem;
    uint32_t* Hxp   = smem + HXP_OFF;        // Hxp[col][raw_r] at col*HXS + raw_r; raw_r = logical+16
    float*   inv_ch = (float*)(smem + ICH_OFF);

    const int t     = threadIdx.x;
    const int strip = blockIdx.x % NSTRIP;
    const int b     = blockIdx.x / NSTRIP;
    const int c0    = strip * TW;
    const float* inb = in + (size_t)b * (HH * WW);

    // phase 0: per-row reciprocals + zero Hxp pad rows (raw 0..15 and 96..111) for 80 cols
    if (t < HH) {
        int lo = max(t - RAD, 0), hi = min(t + RAD, HH - 1);
        inv_ch[t] = 1.0f / (float)(hi - lo + 1);
    }
    if (t < 640) {
        const int col = t >> 3;
        const int c8  = t & 7;
        const int off = col * HXS + ((c8 < 4) ? (c8 * 4) : (96 + (c8 - 4) * 4));
        *(uint4*)(Hxp + off) = make_uint4(0u, 0u, 0u, 0u);
    }

    // phase 1: stage 112 cols x 80 rows of f32 into Xs.
    // Interior strips: pure DMA via global_load_lds (2240 16B chunks, linear LDS dest).
    // Edge strips (0, 37): scalar bounds-checked fallback.
    bool dma = false;
#ifdef HAVE_GLL
    dma = (c0 >= 16) && (c0 + NLOAD - 16 <= WW);
#endif
    if (dma) {
#ifdef HAVE_GLL
        const float* gsrc = inb + (c0 - 16);
        #pragma unroll
        for (int i = 0; i < 3; ++i) {
            const int ck = t + i * NT;                 // chunk id: 4 words at Xs word 4*ck
            if (i < 2 || ck < 2240) {
                const int row = ck / 28;               // 28 chunks per 112-word row
                const int m   = ck - row * 28;
                gload_lds16(gsrc + (size_t)row * WW + 4 * m, smemf + 4 * ck);
            }
        }
#endif
    } else {
        #pragma unroll
        for (int it = 0; it < 3; ++it) {
            const int id = t + it * NT;
            if (it < 2 || id < 2240) {
                const int row = id / 28;
                const int q   = id - row * 28;
                const int gc  = c0 - 16 + 4 * q;
                const float* rp = inb + (size_t)row * WW;
                f32x4 v;
                if (gc >= 0 && gc + 4 <= WW) {
                    v = *(const f32x4*)(rp + gc);
                } else {
                    v.x = (gc     >= 0 && gc     < WW) ? rp[gc]     : 0.f;
                    v.y = (gc + 1 >= 0 && gc + 1 < WW) ? rp[gc + 1] : 0.f;
                    v.z = (gc + 2 >= 0 && gc + 2 < WW) ? rp[gc + 2] : 0.f;
                    v.w = (gc + 3 >= 0 && gc + 3 < WW) ? rp[gc + 3] : 0.f;
                }
                *(f32x4*)(smemf + row * XSW + 4 * q) = v;
            }
        }
    }
    __syncthreads();   // drains vmcnt -> DMA'd Xs visible

    // phase 2: fused horizontal 33-tap sums of x AND x^2 from f32 Xs;
    // packed-f32 pairwise init (v_pk_add/v_pk_fma). 80 rows x 5 segs of 16 cols = 400 threads.
    {
        const int row = t % HH;
        const int seg = t / HH;       // 0..4 active
        if (seg < 5) {
            const float* xr = smemf + row * XSW + seg * 16;
            f32x4 G0  = *(const f32x4*)(xr);
            f32x4 G1  = *(const f32x4*)(xr + 4);
            f32x4 G2  = *(const f32x4*)(xr + 8);
            f32x4 G3  = *(const f32x4*)(xr + 12);
            f32x4 G4  = *(const f32x4*)(xr + 16);
            f32x4 G5  = *(const f32x4*)(xr + 20);
            f32x4 G6  = *(const f32x4*)(xr + 24);
            f32x4 G7  = *(const f32x4*)(xr + 28);
            f32x4 G8  = *(const f32x4*)(xr + 32);
            f32x4 G9  = *(const f32x4*)(xr + 36);
            f32x4 G10 = *(const f32x4*)(xr + 40);
            f32x4 G11 = *(const f32x4*)(xr + 44);
            // initial window F(0..32): packed pairwise over words 0..31 + lone e32.
            // 16 pk_add + 16 pk_fma replace 33 add + 33 fma.
            f32x2 sA = G0.xy + G1.xy;
            f32x2 sB = G0.zw + G1.zw;
            f32x2 qA = G0.xy * G0.xy + G1.xy * G1.xy;   // pk_mul + pk_fma
            f32x2 qB = G0.zw * G0.zw + G1.zw * G1.zw;
            sA += G2.xy; sB += G2.zw; qA += G2.xy * G2.xy; qB += G2.zw * G2.zw;
            sA += G3.xy; sB += G3.zw; qA += G3.xy * G3.xy; qB += G3.zw * G3.zw;
            sA += G4.xy; sB += G4.zw; qA += G4.xy * G4.xy; qB += G4.zw * G4.zw;
            sA += G5.xy; sB += G5.zw; qA += G5.xy * G5.xy; qB += G5.zw * G5.zw;
            sA += G6.xy; sB += G6.zw; qA += G6.xy * G6.xy; qB += G6.zw * G6.zw;
            sA += G7.xy; sB += G7.zw; qA += G7.xy * G7.xy; qB += G7.zw * G7.zw;
            f32x2 sF = sA + sB;
            f32x2 qF = qA + qB;
            const float e32 = G8.x;
            float ax  = sF.x + sF.y + e32;
            float axx = fmaf(e32, e32, qF.x + qF.y);
            uint32_t* hw = Hxp + (seg * 16) * HXS + row + 16;
            #pragma unroll
            for (int k = 0; k < 8; ++k) {
                float fs = F48(2 * k), fe = F48(2 * k + 33);
                float a1x  = ax - fs + fe;
                float a1xx = fmaf(fe, fe, fmaf(-fs, fs, axx));
                hw[(2 * k) * HXS]     = packbf2(ax, axx);
                hw[(2 * k + 1) * HXS] = packbf2(a1x, a1xx);
                if (k != 7) {
                    float fs2 = F48(2 * k + 1), fe2 = F48(2 * k + 34);
                    ax  = a1x - fs2 + fe2;
                    axx = fmaf(fe2, fe2, fmaf(-fs2, fs2, a1xx));
                }
            }
        }
    }
    __syncthreads();

    // phase 3: vertical 33-tap sums of (Sx,Sxx) via pk_add, bands of 16 rows.
    // 80 cols x 5 bands = 400 threads; 12 contiguous b128 reads (words r0..r0+47).
    {
        const int c    = t % TW;
        const int band = t / TW;
        const int gc   = c0 + c;
        if (band < 5 && gc < WW) {
            const int r0 = band * 16;
            const uint32_t* hp = Hxp + c * HXS + r0;   // raw rows r0 .. r0+47
            uint4 R0  = *(const uint4*)(hp);
            uint4 R1  = *(const uint4*)(hp + 4);
            uint4 R2  = *(const uint4*)(hp + 8);
            uint4 R3  = *(const uint4*)(hp + 12);
            uint4 R4  = *(const uint4*)(hp + 16);
            uint4 R5  = *(const uint4*)(hp + 20);
            uint4 R6  = *(const uint4*)(hp + 24);
            uint4 R7  = *(const uint4*)(hp + 28);
            uint4 R8  = *(const uint4*)(hp + 32);
            uint4 R9  = *(const uint4*)(hp + 36);
            uint4 R10 = *(const uint4*)(hp + 40);
            uint4 R11 = *(const uint4*)(hp + 44);
            // init acc = sum of words 0..32 (3 ops/word via pk_add), 2-way split
            f32x2 aA = uw(W48(32));
            f32x2 aB; aB.x = 0.f; aB.y = 0.f;
            #pragma unroll
            for (int q = 0; q < 32; q += 2) {
                aA += uw(W48(q));
                aB += uw(W48(q + 1));
            }
            f32x2 acc = aA + aB;                       // {Sx_v, Sxx_v}
            const float icw = 1.0f / (float)(min(gc + RAD, WW - 1) - max(gc - RAD, 0) + 1);
            f32x4 f0 = *(const f32x4*)(inv_ch + r0);
            f32x4 f1 = *(const f32x4*)(inv_ch + r0 + 4);
            f32x4 f2 = *(const f32x4*)(inv_ch + r0 + 8);
            f32x4 f3 = *(const f32x4*)(inv_ch + r0 + 12);
            float* outb = out + (size_t)b * (HH * WW);
            #pragma unroll
            for (int k = 0; k < 16; ++k) {
                const int r = r0 + k;
                const float ninv = F16(k) * icw;
                f32x2 me = acc * ninv;                 // {mean, E[x^2]} via v_pk_mul
                float var = fmaxf(me.y - me.x * me.x, 1e-24f);
#if defined(__has_builtin) && __has_builtin(__builtin_amdgcn_rsqf)
                float isd = __builtin_amdgcn_rsqf(var);
#else
                float isd = __builtin_amdgcn_rcpf(__builtin_amdgcn_sqrtf(var) + EPSF);
#endif
                float xv = smemf[r * XSW + c + 16];    // f32 x, no unpack
                outb[(size_t)r * WW + gc] = (xv - me.x) * isd;
                if (k != 15) {
                    acc += uw(W48(k + 33)) - uw(W48(k));   // 2x v_pk_add_f32
                }
            }
        }
    }
}

extern "C" void kernel_launch(void* const* d_in, const int* in_sizes, int n_in,
                              void* d_out, int out_size, void* d_ws, size_t ws_size,
                              hipStream_t stream) {
    const float* in = (const float*)d_in[0];
    float* out = (float*)d_out;

    const size_t lds_bytes = (size_t)TOT_WORDS * sizeof(uint32_t);  // 73280
    static bool attr_set = false;
    if (!attr_set) {
        (void)hipFuncSetAttribute((const void*)localnorm_kernel,
                                  hipFuncAttributeMaxDynamicSharedMemorySize,
                                  (int)lds_bytes);
        attr_set = true;
    }

    dim3 grid(BB * NSTRIP);
    dim3 block(NT);
    localnorm_kernel<<<grid, block, lds_bytes, stream>>>(in, out);
}